// Round 1
// baseline (65.591 us; speedup 1.0000x reference)
//
#include <hip/hip_runtime.h>

#define NP 1048576
#define BLOCK 256
#define PPT 4
#define NBLK (NP / (BLOCK * PPT))   /* 1024 */
#define W_IN 0.001f
#define W_OUT 1.0f
#define TOL 1e-8f

__device__ __forceinline__ float rcp_fast(float x) { return __builtin_amdgcn_rcpf(x); }
__device__ __forceinline__ float guardf(float x) { return fabsf(x) > 1e-20f ? x : 1.0f; }

__device__ __forceinline__ void closest_sq_tri(
    float px, float py, float pz,
    float ax, float ay, float az,
    float bx, float by, float bz,
    float cx, float cy, float cz,
    float abx, float aby, float abz,
    float acx, float acy, float acz,
    float cbx, float cby, float cbz,
    float& best)
{
    float apx = px - ax, apy = py - ay, apz = pz - az;
    float d1 = abx*apx + aby*apy + abz*apz;
    float d2 = acx*apx + acy*apy + acz*apz;
    float bpx = px - bx, bpy = py - by, bpz = pz - bz;
    float d3 = abx*bpx + aby*bpy + abz*bpz;
    float d4 = acx*bpx + acy*bpy + acz*bpz;
    float cpx = px - cx, cpy = py - cy, cpz = pz - cz;
    float d5 = abx*cpx + aby*cpy + abz*cpz;
    float d6 = acx*cpx + acy*cpy + acz*cpz;

    float vc = d1*d4 - d3*d2;
    float vb = d5*d2 - d1*d6;
    float va = d3*d6 - d5*d4;

    float rd = rcp_fast(guardf(va + vb + vc));
    float v = vb * rd, w = vc * rd;
    float rx = ax + abx*v + acx*w;
    float ry = ay + aby*v + acy*w;
    float rz = az + abz*v + acz*w;

    float d43 = d4 - d3, d56 = d5 - d6;
    {   // edge BC region
        float t = d43 * rcp_fast(guardf(d43 + d56));
        bool cond = (va <= 0.f) && (d43 >= 0.f) && (d56 >= 0.f);
        rx = cond ? bx + t*cbx : rx;
        ry = cond ? by + t*cby : ry;
        rz = cond ? bz + t*cbz : rz;
    }
    {   // edge AC region
        float t = d2 * rcp_fast(guardf(d2 - d6));
        bool cond = (vb <= 0.f) && (d2 >= 0.f) && (d6 <= 0.f);
        rx = cond ? ax + t*acx : rx;
        ry = cond ? ay + t*acy : ry;
        rz = cond ? az + t*acz : rz;
    }
    {   // edge AB region
        float t = d1 * rcp_fast(guardf(d1 - d3));
        bool cond = (vc <= 0.f) && (d1 >= 0.f) && (d3 <= 0.f);
        rx = cond ? ax + t*abx : rx;
        ry = cond ? ay + t*aby : ry;
        rz = cond ? az + t*abz : rz;
    }
    {   // vertex C
        bool cond = (d6 >= 0.f) && (d5 <= d6);
        rx = cond ? cx : rx; ry = cond ? cy : ry; rz = cond ? cz : rz;
    }
    {   // vertex B
        bool cond = (d3 >= 0.f) && (d4 <= d3);
        rx = cond ? bx : rx; ry = cond ? by : ry; rz = cond ? bz : rz;
    }
    {   // vertex A
        bool cond = (d1 <= 0.f) && (d2 <= 0.f);
        rx = cond ? ax : rx; ry = cond ? ay : ry; rz = cond ? az : rz;
    }
    float ex = px - rx, ey = py - ry, ez = pz - rz;
    best = fminf(best, ex*ex + ey*ey + ez*ez);
}

__global__ __launch_bounds__(BLOCK) void pbl_main(
    const float* __restrict__ pts, const float* __restrict__ hv,
    const float* __restrict__ ht, const float* __restrict__ fn,
    const float* __restrict__ fo, float* __restrict__ ws)
{
    __shared__ float4 s_tri[8][5];   // packed a,b,c,ab,ac,cb per tri (18 floats + pad)
    __shared__ float4 s_nrm[8];      // nx,ny,nz,off
    __shared__ float4 s_vtx[6];      // vx,vy,vz,0
    __shared__ float  s_sum[BLOCK/64];
    __shared__ unsigned s_cnt[BLOCK/64];
    __shared__ float  s_mx[BLOCK/64];

    const int lt = threadIdx.x;
    if (lt < 8) {
        const int t = lt;
        float ax = ht[t*9+0], ay = ht[t*9+1], az = ht[t*9+2];
        float bx = ht[t*9+3], by = ht[t*9+4], bz = ht[t*9+5];
        float cx = ht[t*9+6], cy = ht[t*9+7], cz = ht[t*9+8];
        s_tri[t][0] = make_float4(ax, ay, az, bx);
        s_tri[t][1] = make_float4(by, bz, cx, cy);
        s_tri[t][2] = make_float4(cz, bx-ax, by-ay, bz-az);
        s_tri[t][3] = make_float4(cx-ax, cy-ay, cz-az, cx-bx);
        s_tri[t][4] = make_float4(cy-by, cz-bz, 0.f, 0.f);
        s_nrm[t] = make_float4(fn[t*3+0], fn[t*3+1], fn[t*3+2], fo[t]);
    }
    if (lt < 6) s_vtx[lt] = make_float4(hv[lt*3+0], hv[lt*3+1], hv[lt*3+2], 0.f);
    __syncthreads();

    const int tid = blockIdx.x * BLOCK + lt;
    const float4* p4 = (const float4*)pts;
    float4 f0 = p4[tid*3+0];
    float4 f1 = p4[tid*3+1];
    float4 f2 = p4[tid*3+2];
    float px[PPT] = {f0.x, f0.w, f1.z, f2.y};
    float py[PPT] = {f0.y, f1.x, f1.w, f2.z};
    float pz[PPT] = {f0.z, f1.y, f2.x, f2.w};

    // inside test: max plane violation
    float mv[PPT] = {-1e30f, -1e30f, -1e30f, -1e30f};
    #pragma unroll
    for (int f = 0; f < 8; ++f) {
        float4 n = s_nrm[f];
        #pragma unroll
        for (int i = 0; i < PPT; ++i)
            mv[i] = fmaxf(mv[i], px[i]*n.x + py[i]*n.y + pz[i]*n.z - n.w);
    }

    // min squared distance to hull vertices
    float d2v[PPT] = {1e30f, 1e30f, 1e30f, 1e30f};
    #pragma unroll
    for (int v = 0; v < 6; ++v) {
        float4 q = s_vtx[v];
        #pragma unroll
        for (int i = 0; i < PPT; ++i) {
            float dx = px[i]-q.x, dy = py[i]-q.y, dz = pz[i]-q.z;
            d2v[i] = fminf(d2v[i], dx*dx + dy*dy + dz*dz);
        }
    }

    // min squared distance to hull surface (8 triangles)
    float best[PPT] = {1e30f, 1e30f, 1e30f, 1e30f};
    #pragma unroll
    for (int t = 0; t < 8; ++t) {
        float4 q0 = s_tri[t][0], q1 = s_tri[t][1], q2 = s_tri[t][2];
        float4 q3 = s_tri[t][3], q4 = s_tri[t][4];
        float ax=q0.x, ay=q0.y, az=q0.z, bx=q0.w;
        float by=q1.x, bz=q1.y, cx=q1.z, cy=q1.w;
        float cz=q2.x, abx=q2.y, aby=q2.z, abz=q2.w;
        float acx=q3.x, acy=q3.y, acz=q3.z, cbx=q3.w;
        float cby=q4.x, cbz=q4.y;
        #pragma unroll
        for (int i = 0; i < PPT; ++i)
            closest_sq_tri(px[i], py[i], pz[i], ax,ay,az, bx,by,bz, cx,cy,cz,
                           abx,aby,abz, acx,acy,acz, cbx,cby,cbz, best[i]);
    }

    float sum_in = 0.f;
    unsigned cnt_in = 0;
    float mx_out = 0.f;
    #pragma unroll
    for (int i = 0; i < PPT; ++i) {
        bool inside = mv[i] <= TOL;
        sum_in += inside ? d2v[i] : 0.f;
        cnt_in += inside ? 1u : 0u;
        mx_out  = inside ? mx_out : fmaxf(mx_out, best[i]);
    }

    // wave reduce (64 lanes)
    #pragma unroll
    for (int o = 32; o > 0; o >>= 1) {
        sum_in += __shfl_down(sum_in, o);
        cnt_in += __shfl_down(cnt_in, o);
        mx_out  = fmaxf(mx_out, __shfl_down(mx_out, o));
    }
    const int wave = lt >> 6, lane = lt & 63;
    if (lane == 0) { s_sum[wave] = sum_in; s_cnt[wave] = cnt_in; s_mx[wave] = mx_out; }
    __syncthreads();
    if (lt == 0) {
        float S = 0.f; unsigned C = 0; float M = 0.f;
        #pragma unroll
        for (int i = 0; i < BLOCK/64; ++i) { S += s_sum[i]; C += s_cnt[i]; M = fmaxf(M, s_mx[i]); }
        atomicAdd(&ws[0], S);
        atomicAdd((unsigned*)&ws[1], C);
        atomicMax((unsigned*)&ws[2], __float_as_uint(M));
    }
}

__global__ void pbl_final(const float* __restrict__ ws, float* __restrict__ out)
{
    float sum = ws[0];
    unsigned cnt = ((const unsigned*)ws)[1];
    float mx = __uint_as_float(((const unsigned*)ws)[2]);
    unsigned nout = (unsigned)NP - cnt;
    float li = (cnt > 0) ? W_IN * sum / (float)cnt : 0.f;
    float lo = (nout > 0) ? W_OUT * mx : 0.f;
    out[0] = li + lo;
}

extern "C" void kernel_launch(void* const* d_in, const int* in_sizes, int n_in,
                              void* d_out, int out_size, void* d_ws, size_t ws_size,
                              hipStream_t stream) {
    const float* pts = (const float*)d_in[0];
    const float* hv  = (const float*)d_in[1];
    const float* ht  = (const float*)d_in[2];
    const float* fn  = (const float*)d_in[3];
    const float* fo  = (const float*)d_in[4];
    float* ws = (float*)d_ws;
    float* out = (float*)d_out;

    hipMemsetAsync(ws, 0, 16, stream);
    pbl_main<<<NBLK, BLOCK, 0, stream>>>(pts, hv, ht, fn, fo, ws);
    pbl_final<<<1, 1, 0, stream>>>(ws, out);
}

// Round 2
// 50.269 us; speedup vs baseline: 1.3048x; 1.3048x over previous
//
#include <hip/hip_runtime.h>

#define NP 1048576
#define BLOCK 256
#define PPT 4
#define NBLK (NP / (BLOCK * PPT))   /* 1024 */
#define W_IN 0.001f
#define W_OUT 1.0f
#define TOL 1e-8f

__global__ __launch_bounds__(BLOCK) void pbl_main(
    const float* __restrict__ pts, const float* __restrict__ hv,
    const float* __restrict__ ht, const float* __restrict__ fn,
    const float* __restrict__ fo, float* __restrict__ ws)
{
    __shared__ float4 s_nrm[8];      // nx,ny,nz,-off
    __shared__ float4 s_vtx[6];      // vx,vy,vz,0
    __shared__ float  s_sum[BLOCK/64];
    __shared__ unsigned s_cnt[BLOCK/64];
    __shared__ float  s_mx[BLOCK/64];

    const int lt = threadIdx.x;
    if (lt < 8) s_nrm[lt] = make_float4(fn[lt*3+0], fn[lt*3+1], fn[lt*3+2], -fo[lt]);
    if (lt < 6) s_vtx[lt] = make_float4(hv[lt*3+0], hv[lt*3+1], hv[lt*3+2], 0.f);
    __syncthreads();

    const int tid = blockIdx.x * BLOCK + lt;
    const float4* p4 = (const float4*)pts;
    float4 f0 = p4[tid*3+0];
    float4 f1 = p4[tid*3+1];
    float4 f2 = p4[tid*3+2];
    float px[PPT] = {f0.x, f0.w, f1.z, f2.y};
    float py[PPT] = {f0.y, f1.x, f1.w, f2.z};
    float pz[PPT] = {f0.z, f1.y, f2.x, f2.w};

    // inside test: max plane violation (uses actual fn/fo inputs, matches ref)
    float mv[PPT] = {-1e30f, -1e30f, -1e30f, -1e30f};
    #pragma unroll
    for (int f = 0; f < 8; ++f) {
        float4 n = s_nrm[f];
        #pragma unroll
        for (int i = 0; i < PPT; ++i)
            mv[i] = fmaxf(mv[i], fmaf(px[i], n.x, fmaf(py[i], n.y, fmaf(pz[i], n.z, n.w))));
    }

    // min squared distance to hull vertices (generic 6-vertex loop)
    float d2v[PPT] = {1e30f, 1e30f, 1e30f, 1e30f};
    #pragma unroll
    for (int v = 0; v < 6; ++v) {
        float4 q = s_vtx[v];
        #pragma unroll
        for (int i = 0; i < PPT; ++i) {
            float dx = px[i]-q.x, dy = py[i]-q.y, dz = pz[i]-q.z;
            d2v[i] = fminf(d2v[i], fmaf(dx, dx, fmaf(dy, dy, dz*dz)));
        }
    }

    // exact squared distance to octahedron (L1 unit ball): fold to |p|,
    // project onto simplex {u>=0, sum u = 1} (sort + active-set rule)
    float sq[PPT];
    #pragma unroll
    for (int i = 0; i < PPT; ++i) {
        float ux = fabsf(px[i]), uy = fabsf(py[i]), uz = fabsf(pz[i]);
        float hi = fmaxf(ux, fmaxf(uy, uz));
        float lo = fminf(ux, fminf(uy, uz));
        float s  = ux + uy + uz;
        float mid = s - hi - lo;
        float t3 = (s - 1.f) * (1.f/3.f);
        float t2 = (hi + mid - 1.f) * 0.5f;
        float t1 = hi - 1.f;
        float d2_3 = 3.f * t3 * t3;
        float d2_2 = fmaf(lo, lo, 2.f * t2 * t2);
        float d2_1 = fmaf(t1, t1, fmaf(mid, mid, lo * lo));
        sq[i] = (lo > t3) ? d2_3 : ((mid > t2) ? d2_2 : d2_1);
    }

    float sum_in = 0.f;
    unsigned cnt_in = 0;
    float mx_out = 0.f;
    #pragma unroll
    for (int i = 0; i < PPT; ++i) {
        bool inside = mv[i] <= TOL;
        sum_in += inside ? d2v[i] : 0.f;
        cnt_in += inside ? 1u : 0u;
        mx_out  = inside ? mx_out : fmaxf(mx_out, sq[i]);
    }

    // wave reduce (64 lanes)
    #pragma unroll
    for (int o = 32; o > 0; o >>= 1) {
        sum_in += __shfl_down(sum_in, o);
        cnt_in += __shfl_down(cnt_in, o);
        mx_out  = fmaxf(mx_out, __shfl_down(mx_out, o));
    }
    const int wave = lt >> 6, lane = lt & 63;
    if (lane == 0) { s_sum[wave] = sum_in; s_cnt[wave] = cnt_in; s_mx[wave] = mx_out; }
    __syncthreads();
    if (lt == 0) {
        float S = 0.f; unsigned C = 0; float M = 0.f;
        #pragma unroll
        for (int i = 0; i < BLOCK/64; ++i) { S += s_sum[i]; C += s_cnt[i]; M = fmaxf(M, s_mx[i]); }
        atomicAdd(&ws[0], S);
        atomicAdd((unsigned*)&ws[1], C);
        atomicMax((unsigned*)&ws[2], __float_as_uint(M));
    }
}

__global__ void pbl_final(const float* __restrict__ ws, float* __restrict__ out)
{
    float sum = ws[0];
    unsigned cnt = ((const unsigned*)ws)[1];
    float mx = __uint_as_float(((const unsigned*)ws)[2]);
    unsigned nout = (unsigned)NP - cnt;
    float li = (cnt > 0) ? W_IN * sum / (float)cnt : 0.f;
    float lo = (nout > 0) ? W_OUT * mx : 0.f;
    out[0] = li + lo;
}

extern "C" void kernel_launch(void* const* d_in, const int* in_sizes, int n_in,
                              void* d_out, int out_size, void* d_ws, size_t ws_size,
                              hipStream_t stream) {
    const float* pts = (const float*)d_in[0];
    const float* hv  = (const float*)d_in[1];
    const float* ht  = (const float*)d_in[2];
    const float* fn  = (const float*)d_in[3];
    const float* fo  = (const float*)d_in[4];
    float* ws = (float*)d_ws;
    float* out = (float*)d_out;

    hipMemsetAsync(ws, 0, 16, stream);
    pbl_main<<<NBLK, BLOCK, 0, stream>>>(pts, hv, ht, fn, fo, ws);
    pbl_final<<<1, 1, 0, stream>>>(ws, out);
}

// Round 3
// 11.470 us; speedup vs baseline: 5.7184x; 4.3827x over previous
//
#include <hip/hip_runtime.h>

#define NP 1048576
#define BLOCK 256
#define PPT 4
#define NBLK (NP / (BLOCK * PPT))   /* 1024 */
#define W_IN 0.001f
#define W_OUT 1.0f
#define TOL 1e-8f

__global__ __launch_bounds__(BLOCK) void pbl_main(
    const float* __restrict__ pts, const float* __restrict__ hv,
    const float* __restrict__ ht, const float* __restrict__ fn,
    const float* __restrict__ fo, float* __restrict__ ws)
{
    __shared__ float4 s_nrm[8];      // nx,ny,nz,-off
    __shared__ float4 s_vtx[6];      // vx,vy,vz,0
    __shared__ float  s_sum[BLOCK/64];
    __shared__ float  s_cnt[BLOCK/64];
    __shared__ float  s_mx[BLOCK/64];

    const int lt = threadIdx.x;
    if (lt < 8) s_nrm[lt] = make_float4(fn[lt*3+0], fn[lt*3+1], fn[lt*3+2], -fo[lt]);
    if (lt < 6) s_vtx[lt] = make_float4(hv[lt*3+0], hv[lt*3+1], hv[lt*3+2], 0.f);
    __syncthreads();

    const int tid = blockIdx.x * BLOCK + lt;
    const float4* p4 = (const float4*)pts;
    float4 f0 = p4[tid*3+0];
    float4 f1 = p4[tid*3+1];
    float4 f2 = p4[tid*3+2];
    float px[PPT] = {f0.x, f0.w, f1.z, f2.y};
    float py[PPT] = {f0.y, f1.x, f1.w, f2.z};
    float pz[PPT] = {f0.z, f1.y, f2.x, f2.w};

    // inside test: max plane violation (uses actual fn/fo inputs, matches ref)
    float mv[PPT] = {-1e30f, -1e30f, -1e30f, -1e30f};
    #pragma unroll
    for (int f = 0; f < 8; ++f) {
        float4 n = s_nrm[f];
        #pragma unroll
        for (int i = 0; i < PPT; ++i)
            mv[i] = fmaxf(mv[i], fmaf(px[i], n.x, fmaf(py[i], n.y, fmaf(pz[i], n.z, n.w))));
    }

    // min squared distance to hull vertices (generic 6-vertex loop)
    float d2v[PPT] = {1e30f, 1e30f, 1e30f, 1e30f};
    #pragma unroll
    for (int v = 0; v < 6; ++v) {
        float4 q = s_vtx[v];
        #pragma unroll
        for (int i = 0; i < PPT; ++i) {
            float dx = px[i]-q.x, dy = py[i]-q.y, dz = pz[i]-q.z;
            d2v[i] = fminf(d2v[i], fmaf(dx, dx, fmaf(dy, dy, dz*dz)));
        }
    }

    // exact squared distance to octahedron (L1 unit ball): fold to |p|,
    // project onto simplex {u>=0, sum u = 1} (sort + active-set rule)
    float sq[PPT];
    #pragma unroll
    for (int i = 0; i < PPT; ++i) {
        float ux = fabsf(px[i]), uy = fabsf(py[i]), uz = fabsf(pz[i]);
        float hi = fmaxf(ux, fmaxf(uy, uz));
        float lo = fminf(ux, fminf(uy, uz));
        float s  = ux + uy + uz;
        float mid = s - hi - lo;
        float t3 = (s - 1.f) * (1.f/3.f);
        float t2 = (hi + mid - 1.f) * 0.5f;
        float t1 = hi - 1.f;
        float d2_3 = 3.f * t3 * t3;
        float d2_2 = fmaf(lo, lo, 2.f * t2 * t2);
        float d2_1 = fmaf(t1, t1, fmaf(mid, mid, lo * lo));
        sq[i] = (lo > t3) ? d2_3 : ((mid > t2) ? d2_2 : d2_1);
    }

    float sum_in = 0.f;
    float cnt_in = 0.f;
    float mx_out = 0.f;
    #pragma unroll
    for (int i = 0; i < PPT; ++i) {
        bool inside = mv[i] <= TOL;
        sum_in += inside ? d2v[i] : 0.f;
        cnt_in += inside ? 1.f : 0.f;
        mx_out  = inside ? mx_out : fmaxf(mx_out, sq[i]);
    }

    // wave reduce (64 lanes)
    #pragma unroll
    for (int o = 32; o > 0; o >>= 1) {
        sum_in += __shfl_down(sum_in, o);
        cnt_in += __shfl_down(cnt_in, o);
        mx_out  = fmaxf(mx_out, __shfl_down(mx_out, o));
    }
    const int wave = lt >> 6, lane = lt & 63;
    if (lane == 0) { s_sum[wave] = sum_in; s_cnt[wave] = cnt_in; s_mx[wave] = mx_out; }
    __syncthreads();
    if (lt == 0) {
        float S = 0.f, C = 0.f, M = 0.f;
        #pragma unroll
        for (int i = 0; i < BLOCK/64; ++i) { S += s_sum[i]; C += s_cnt[i]; M = fmaxf(M, s_mx[i]); }
        // per-block partials at distinct addresses: no atomic contention
        ws[blockIdx.x]          = S;
        ws[NBLK + blockIdx.x]   = C;
        ws[2*NBLK + blockIdx.x] = M;
    }
}

__global__ __launch_bounds__(256) void pbl_final(const float* __restrict__ ws, float* __restrict__ out)
{
    __shared__ float s_s[4], s_c[4], s_m[4];
    const int lt = threadIdx.x;
    const float4* s4 = (const float4*)ws;             // sums
    const float4* c4 = (const float4*)(ws + NBLK);    // counts
    const float4* m4 = (const float4*)(ws + 2*NBLK);  // maxes
    float4 sv = s4[lt], cv = c4[lt], mv = m4[lt];
    float S = sv.x + sv.y + sv.z + sv.w;
    float C = cv.x + cv.y + cv.z + cv.w;
    float M = fmaxf(fmaxf(mv.x, mv.y), fmaxf(mv.z, mv.w));
    #pragma unroll
    for (int o = 32; o > 0; o >>= 1) {
        S += __shfl_down(S, o);
        C += __shfl_down(C, o);
        M  = fmaxf(M, __shfl_down(M, o));
    }
    const int wave = lt >> 6, lane = lt & 63;
    if (lane == 0) { s_s[wave] = S; s_c[wave] = C; s_m[wave] = M; }
    __syncthreads();
    if (lt == 0) {
        S = s_s[0] + s_s[1] + s_s[2] + s_s[3];
        C = s_c[0] + s_c[1] + s_c[2] + s_c[3];
        M = fmaxf(fmaxf(s_m[0], s_m[1]), fmaxf(s_m[2], s_m[3]));
        float li = (C > 0.f) ? W_IN * S / C : 0.f;
        float nout = (float)NP - C;
        float lo = (nout > 0.f) ? W_OUT * M : 0.f;
        out[0] = li + lo;
    }
}

extern "C" void kernel_launch(void* const* d_in, const int* in_sizes, int n_in,
                              void* d_out, int out_size, void* d_ws, size_t ws_size,
                              hipStream_t stream) {
    const float* pts = (const float*)d_in[0];
    const float* hv  = (const float*)d_in[1];
    const float* ht  = (const float*)d_in[2];
    const float* fn  = (const float*)d_in[3];
    const float* fo  = (const float*)d_in[4];
    float* ws = (float*)d_ws;
    float* out = (float*)d_out;

    pbl_main<<<NBLK, BLOCK, 0, stream>>>(pts, hv, ht, fn, fo, ws);
    pbl_final<<<1, 256, 0, stream>>>(ws, out);
}